// Round 11
// baseline (179.271 us; speedup 1.0000x reference)
//
#include <hip/hip_runtime.h>

// SelfAttention: out = softmax((x Wq^T)(x Wk^T)^T / 32) (x Wv^T)
// N=4096, D=1024, f32 in/out; bf16 MFMA compute.
// v11 = r9 core (best: 141.7us; 256x128 tile, 4 waves, wave-tile 128x64,
// BK=32, 2-buf 48KiB LDS, prefetch-1 + vmcnt(6), conflict-free XOR swizzle,
// XCD swizzle, setprio, 2 blocks/CU; gload_lds bf16 staging + separate cast)
// + PV epilogue writes normalized f32 via atomicAdd (2 adds/address,
//   commutative -> deterministic); reduce_pv and bf16 partials DELETED.
// r10's fused-cast QKV REVERTED (reg-staged f32 path was HBM/latency-bound).

typedef __attribute__((ext_vector_type(8))) __bf16 bf16x8;
typedef __attribute__((ext_vector_type(4))) float floatx4;

#define GLB_AS __attribute__((address_space(1)))
#define LDS_AS __attribute__((address_space(3)))

static __device__ __forceinline__ unsigned short f2bf_u16(float f) {
  union { float f; unsigned u; } x; x.f = f;
  unsigned r = x.u;
  r += 0x7fffu + ((r >> 16) & 1u);   // RNE
  return (unsigned short)(r >> 16);
}

// ---------------- fused cast f32 -> bf16 (x + Wq + Wk + Wv) ----------------
__global__ __launch_bounds__(256) void cast_all(const float* __restrict__ x,
                                                const float* __restrict__ Wq,
                                                const float* __restrict__ Wk,
                                                const float* __restrict__ Wv,
                                                unsigned short* __restrict__ xb,
                                                unsigned short* __restrict__ wb) {
  const int i = blockIdx.x * 256 + threadIdx.x;   // float4 index
  const int NX4 = 4096 * 1024 / 4;
  const int NW4 = 1024 * 1024 / 4;
  const float* src; unsigned short* dst; int k;
  if (i < NX4)                { src = x;  dst = xb;                   k = i; }
  else if (i < NX4 + NW4)     { src = Wq; dst = wb;                   k = i - NX4; }
  else if (i < NX4 + 2 * NW4) { src = Wk; dst = wb + 1024 * 1024;     k = i - NX4 - NW4; }
  else                        { src = Wv; dst = wb + 2 * 1024 * 1024; k = i - NX4 - 2 * NW4; }
  float4 v = reinterpret_cast<const float4*>(src)[k];
  ushort4 o = make_ushort4(f2bf_u16(v.x), f2bf_u16(v.y), f2bf_u16(v.z), f2bf_u16(v.w));
  reinterpret_cast<ushort4*>(dst)[k] = o;
}

// ---------------- collapse rsp[64][4096] -> rs[4096] ----------------
__global__ __launch_bounds__(256) void collapse_rs(const float* __restrict__ rsp,
                                                   float* __restrict__ rs) {
  const int r = blockIdx.x * 256 + threadIdx.x;
  float s = 0.f;
#pragma unroll
  for (int j = 0; j < 64; ++j) s += rsp[j * 4096 + r];
  rs[r] = s;
}

// ---------------- GEMM: C[M,N] = epi(scale * A[M,K] * B[N,K]^T) ----------------
// EPI: 0 = PV  (atomicAdd of acc/rs[m] into f32 out c[0]; rs in c[1])
//      2 = S   (bf16 store of exp to c[0]; per-(colblock,wave) row-sum partials to c[1])
//      3 = QKV (col0<2048: bf16 -> qkb c[0]; col0>=2048: transposed -> vT c[1])
struct GemmOuts { void* c[4]; int ldc[4]; };

template <int EPI>
__global__ __launch_bounds__(256, 2) void gemm_bt(const unsigned short* __restrict__ A,
                                                  const unsigned short* __restrict__ B,
                                                  GemmOuts outs, int lda, int ldb,
                                                  int klen, float scale) {
  // LDS: 2 bufs x (A [256][32] + B [128][32]) = 24576 elems = 48 KiB
  __shared__ unsigned short sh[24576];
  const int t = threadIdx.x;
  const int w = t >> 6, lane = t & 63;
  const int wm = w >> 1, wn = w & 1;        // 2x2 wave grid, wave tile 128x64
  // XCD-aware bijective block swizzle (nwg % 8 == 0 for all grids here)
  const int gx = gridDim.x;
  const int nwg = gx * gridDim.y;
  int bid = blockIdx.y * gx + blockIdx.x;
  bid = (bid & 7) * (nwg >> 3) + (bid >> 3);
  const int row0 = (bid / gx) * 256;
  const int col0 = (bid % gx) * 128;
  const int z = blockIdx.z;
  const int kstart = z * klen;
  const int NT = klen >> 5;                 // K-tiles of 32 (NT >= 2)

  // staging: 6 x 16B per thread per K-tile (A: 4 row-chunks of 64, B: 2).
  // Inverse-swizzled global col (rule 21): LDS linear dest, source pre-permuted.
  const int srow = t >> 2;                                  // 0..63
  const int scbe = (((t & 3) ^ ((t >> 3) & 3)) << 3);       // swizzled src col (elems)
  const unsigned short* gA0 = A + (size_t)(row0 + srow) * lda + kstart + scbe;
  const unsigned short* gA1 = gA0 + (size_t)64 * lda;
  const unsigned short* gA2 = gA0 + (size_t)128 * lda;
  const unsigned short* gA3 = gA0 + (size_t)192 * lda;
  const unsigned short* gB0 = B + (size_t)(col0 + srow) * ldb + kstart + scbe;
  const unsigned short* gB1 = gB0 + (size_t)64 * ldb;

#define STAGE(tl_) do { \
    const int bb_ = ((tl_) & 1) * 12288; \
    __builtin_amdgcn_global_load_lds((const GLB_AS void*)(gA0 + (tl_) * 32), \
        (LDS_AS void*)&sh[bb_ + t * 8], 16, 0, 0); \
    __builtin_amdgcn_global_load_lds((const GLB_AS void*)(gA1 + (tl_) * 32), \
        (LDS_AS void*)&sh[bb_ + 2048 + t * 8], 16, 0, 0); \
    __builtin_amdgcn_global_load_lds((const GLB_AS void*)(gA2 + (tl_) * 32), \
        (LDS_AS void*)&sh[bb_ + 4096 + t * 8], 16, 0, 0); \
    __builtin_amdgcn_global_load_lds((const GLB_AS void*)(gA3 + (tl_) * 32), \
        (LDS_AS void*)&sh[bb_ + 6144 + t * 8], 16, 0, 0); \
    __builtin_amdgcn_global_load_lds((const GLB_AS void*)(gB0 + (tl_) * 32), \
        (LDS_AS void*)&sh[bb_ + 8192 + t * 8], 16, 0, 0); \
    __builtin_amdgcn_global_load_lds((const GLB_AS void*)(gB1 + (tl_) * 32), \
        (LDS_AS void*)&sh[bb_ + 10240 + t * 8], 16, 0, 0); \
  } while (0)

  // ds_read element offsets (swizzled; same conflict-free family as r2-r9)
  const int fr = lane & 15;
  const int sg = (((lane >> 4) ^ ((lane >> 1) & 3)) << 3);
  int aofs[8], bofs[4];
#pragma unroll
  for (int mf = 0; mf < 8; ++mf) aofs[mf] = ((wm * 128 + mf * 16 + fr) << 5) + sg;
#pragma unroll
  for (int nf = 0; nf < 4; ++nf) bofs[nf] = 8192 + ((wn * 64 + nf * 16 + fr) << 5) + sg;

  floatx4 acc[8][4] = {};

  STAGE(0);

  for (int tile = 0; tile < NT; ++tile) {
    if (tile + 1 < NT) {
      STAGE(tile + 1);
      asm volatile("s_waitcnt vmcnt(6)" ::: "memory");   // tile's own 6 loads landed
    } else {
      asm volatile("s_waitcnt vmcnt(0)" ::: "memory");
    }
    __builtin_amdgcn_s_barrier();   // buf[tile&1] ready for all waves

    const int bo = (tile & 1) * 12288;
    bf16x8 af[8], bf[4];
#pragma unroll
    for (int mf = 0; mf < 8; ++mf) af[mf] = *(const bf16x8*)&sh[bo + aofs[mf]];
#pragma unroll
    for (int nf = 0; nf < 4; ++nf) bf[nf] = *(const bf16x8*)&sh[bo + bofs[nf]];
    // T5: 2 independent blocks/CU = role-diverse waves on each SIMD
    __builtin_amdgcn_s_setprio(1);
#pragma unroll
    for (int mf = 0; mf < 8; ++mf)
#pragma unroll
      for (int nf = 0; nf < 4; ++nf)
        acc[mf][nf] = __builtin_amdgcn_mfma_f32_16x16x32_bf16(af[mf], bf[nf], acc[mf][nf], 0, 0, 0);
    __builtin_amdgcn_s_setprio(0);

    __builtin_amdgcn_s_barrier();   // all waves done reading buf[tile&1]
  }
#undef STAGE

  // epilogue: C col = lane&15, row = (lane>>4)*4 + r  [m89-verified]
  const int er = (lane >> 4) * 4;
  const int ec = lane & 15;

  if (EPI == 0) {
    // PV: out[m][n] += acc / rs[m]  (2 atomic adds per address, commutative
    // -> deterministic; out pre-zeroed by hipMemsetAsync)
    float* Of = (float*)outs.c[0];
    const float* rsv = (const float*)outs.c[1];
#pragma unroll
    for (int mf = 0; mf < 8; ++mf) {
#pragma unroll
      for (int r = 0; r < 4; ++r) {
        const int m = row0 + wm * 128 + mf * 16 + er + r;
        const float inv = 1.0f / rsv[m];
#pragma unroll
        for (int nf = 0; nf < 4; ++nf) {
          const int n = col0 + wn * 64 + nf * 16 + ec;
          atomicAdd(&Of[(size_t)m * 1024 + n], acc[mf][nf][r] * inv);
        }
      }
    }
  } else if (EPI == 2) {
    // S: P = bf16(exp(scale*acc)); row-sum partials -> rsp[(col0>>7)*2+wn][m]
    unsigned short* Pb = (unsigned short*)outs.c[0];
    float* rsp = (float*)outs.c[1];
    const int ldc = outs.ldc[0];
    const int rj = ((col0 >> 7) * 2 + wn) * 4096;
#pragma unroll
    for (int mf = 0; mf < 8; ++mf) {
#pragma unroll
      for (int r = 0; r < 4; ++r) {
        const int m = row0 + wm * 128 + mf * 16 + er + r;
        float rsum = 0.f;
#pragma unroll
        for (int nf = 0; nf < 4; ++nf) {
          const float e = __expf(acc[mf][nf][r] * scale);
          Pb[(size_t)m * ldc + (col0 + wn * 64 + nf * 16 + ec)] = f2bf_u16(e);
          rsum += e;
        }
        rsum += __shfl_xor(rsum, 1);
        rsum += __shfl_xor(rsum, 2);
        rsum += __shfl_xor(rsum, 4);
        rsum += __shfl_xor(rsum, 8);
        if (ec == 0) rsp[rj + m] = rsum;   // plain store, unique address
      }
    }
  } else {
    // QKV: q,k -> qkb [4096][2048]; v -> vT [1024][4096] (transposed)
    if (col0 < 2048) {
      unsigned short* qkb = (unsigned short*)outs.c[0];
#pragma unroll
      for (int mf = 0; mf < 8; ++mf)
#pragma unroll
        for (int nf = 0; nf < 4; ++nf)
#pragma unroll
          for (int r = 0; r < 4; ++r)
            qkb[(size_t)(row0 + wm * 128 + mf * 16 + er + r) * 2048 +
                (col0 + wn * 64 + nf * 16 + ec)] = f2bf_u16(acc[mf][nf][r]);
    } else {
      unsigned short* vT = (unsigned short*)outs.c[1];
#pragma unroll
      for (int mf = 0; mf < 8; ++mf)
#pragma unroll
        for (int nf = 0; nf < 4; ++nf) {
          const int n = (col0 - 2048) + wn * 64 + nf * 16 + ec;
          const int mb = row0 + wm * 128 + mf * 16 + er;
          ushort4 o = make_ushort4(f2bf_u16(acc[mf][nf][0]), f2bf_u16(acc[mf][nf][1]),
                                   f2bf_u16(acc[mf][nf][2]), f2bf_u16(acc[mf][nf][3]));
          *reinterpret_cast<ushort4*>(&vT[(size_t)n * 4096 + mb]) = o;
        }
    }
  }
}

extern "C" void kernel_launch(void* const* d_in, const int* in_sizes, int n_in,
                              void* d_out, int out_size, void* d_ws, size_t ws_size,
                              hipStream_t stream) {
  const float* x  = (const float*)d_in[0];
  const float* Wq = (const float*)d_in[1];
  const float* Wk = (const float*)d_in[2];
  const float* Wv = (const float*)d_in[3];
  float* out = (float*)d_out;

  const int N = 4096, D = 1024;

  // workspace (~72 MB):
  // [0,32)   P bf16 [4096][4096] = exp(scores)
  // [32,48)  qkb bf16 [4096][2048]  (q | k)
  // [48,56)  vT bf16 [1024][4096]
  // [56,64)  xb bf16 [4096][1024]
  // [64,70)  wb bf16 [3072][1024] (Wq;Wk;Wv)
  // [70,71)  rsp f32 [64][4096] row-sum partials
  // [71,..)  rs f32 [4096]
  char* ws = (char*)d_ws;
  unsigned short* P   = (unsigned short*)ws;
  unsigned short* qkb = (unsigned short*)(ws + (32u << 20));
  unsigned short* vT  = (unsigned short*)(ws + (48u << 20));
  unsigned short* xb  = (unsigned short*)(ws + (56u << 20));
  unsigned short* wb  = (unsigned short*)(ws + (64u << 20));
  float*          rsp = (float*)(ws + (70u << 20));
  float*          rs  = (float*)(ws + (71u << 20));

  // zero the output accumulator (async, graph-capturable)
  hipMemsetAsync(out, 0, (size_t)out_size * sizeof(float), stream);

  // fused casts
  cast_all<<<7168, 256, 0, stream>>>(x, Wq, Wk, Wv, xb, wb);

  // qkv = x @ [Wq;Wk;Wv]^T : q,k -> qkb; v -> vT (transposed in epilogue)
  GemmOuts oq; oq.c[0] = qkb; oq.c[1] = vT; oq.c[2] = oq.c[3] = qkb;
  oq.ldc[0] = 2048; oq.ldc[1] = 4096; oq.ldc[2] = oq.ldc[3] = 2048;
  gemm_bt<3><<<dim3(3 * D / 128, N / 256, 1), 256, 0, stream>>>(xb, wb, oq, D, D, D, 1.0f);

  // P = exp((q @ k^T)/32); rsp = row-sum partials (no atomics)
  GemmOuts os; os.c[0] = P; os.c[1] = rsp; os.c[2] = os.c[3] = P;
  os.ldc[0] = N; os.ldc[1] = 0; os.ldc[2] = os.ldc[3] = N;
  gemm_bt<2><<<dim3(N / 128, N / 256, 1), 256, 0, stream>>>(qkb, qkb + D, os, 2 * D, 2 * D, D, 0.03125f);

  // rs = total row sums
  collapse_rs<<<16, 256, 0, stream>>>(rsp, rs);

  // out += (P @ v) / rs[row], split-K x2, atomic f32 (deterministic: 2 adds/addr)
  GemmOuts op; op.c[0] = out; op.c[1] = rs; op.c[2] = op.c[3] = out;
  op.ldc[0] = D; op.ldc[1] = 0; op.ldc[2] = op.ldc[3] = D;
  gemm_bt<0><<<dim3(D / 128, N / 256, 2), 256, 0, stream>>>(P, vT, op, N, N, N / 2, 1.0f);
}

// Round 12
// 138.087 us; speedup vs baseline: 1.2982x; 1.2982x over previous
//
#include <hip/hip_runtime.h>

// SelfAttention: out = softmax((x Wq^T)(x Wk^T)^T / 32) (x Wv^T)
// N=4096, D=1024, f32 in/out; bf16 MFMA compute.
// v12 = r9 (best: 141.7us) with S switched to an 8-phase 256x256 kernel
// (m201/m248 schedule): BK=64, 8 waves (2Mx4N), 2 dbuf x 4 half-regions,
// per-phase {ds_read quadrant | stage 1 half | barrier | lgkm0 | 16 MFMA |
// barrier}, vmcnt(4) at phases 4/8 only (vmcnt(0) last iter), 3-bit XOR
// swizzle for 128B rows. PV/QKV/cast/reduce verbatim from r9 (PV = control).

typedef __attribute__((ext_vector_type(8))) __bf16 bf16x8;
typedef __attribute__((ext_vector_type(4))) float floatx4;

#define GLB_AS __attribute__((address_space(1)))
#define LDS_AS __attribute__((address_space(3)))

static __device__ __forceinline__ unsigned short f2bf_u16(float f) {
  union { float f; unsigned u; } x; x.f = f;
  unsigned r = x.u;
  r += 0x7fffu + ((r >> 16) & 1u);   // RNE
  return (unsigned short)(r >> 16);
}
static __device__ __forceinline__ float bf2f(unsigned short u) {
  union { unsigned u; float f; } x; x.u = ((unsigned)u) << 16; return x.f;
}

// ---------------- fused cast f32 -> bf16 (x + Wq + Wk + Wv) ----------------
__global__ __launch_bounds__(256) void cast_all(const float* __restrict__ x,
                                                const float* __restrict__ Wq,
                                                const float* __restrict__ Wk,
                                                const float* __restrict__ Wv,
                                                unsigned short* __restrict__ xb,
                                                unsigned short* __restrict__ wb) {
  const int i = blockIdx.x * 256 + threadIdx.x;   // float4 index
  const int NX4 = 4096 * 1024 / 4;
  const int NW4 = 1024 * 1024 / 4;
  const float* src; unsigned short* dst; int k;
  if (i < NX4)                { src = x;  dst = xb;                   k = i; }
  else if (i < NX4 + NW4)     { src = Wq; dst = wb;                   k = i - NX4; }
  else if (i < NX4 + 2 * NW4) { src = Wk; dst = wb + 1024 * 1024;     k = i - NX4 - NW4; }
  else                        { src = Wv; dst = wb + 2 * 1024 * 1024; k = i - NX4 - 2 * NW4; }
  float4 v = reinterpret_cast<const float4*>(src)[k];
  ushort4 o = make_ushort4(f2bf_u16(v.x), f2bf_u16(v.y), f2bf_u16(v.z), f2bf_u16(v.w));
  reinterpret_cast<ushort4*>(dst)[k] = o;
}

// ================= 8-phase 256x256 S-GEMM =================
// P = bf16(exp(scale * A B^T)); row-sum partials -> rsp[64][4096].
// A=q [4096][2048ld], B=k [4096][2048ld], K=1024 (NT=16 tiles of 64, NI=8).
__global__ __launch_bounds__(512, 2) void gemm8p_s(const unsigned short* __restrict__ A,
                                                   const unsigned short* __restrict__ B,
                                                   unsigned short* __restrict__ Pb,
                                                   float* __restrict__ rsp,
                                                   int lda, int ldb, int ldc,
                                                   float scale) {
  // LDS: 2 dbuf x { A:[2 halves][128 rows][64], B: same } = 128 KiB
  __shared__ unsigned short sh[65536];
  const int t = threadIdx.x;
  const int w = t >> 6, lane = t & 63;
  const int wm = w >> 2, wn = w & 3;          // 2x4 waves, wave tile 128x64
  const int gx = gridDim.x;                   // 16
  const int nwg = gx * gridDim.y;             // 256 (%8==0)
  int bid = blockIdx.y * gx + blockIdx.x;
  bid = (bid & 7) * (nwg >> 3) + (bid >> 3);  // XCD swizzle
  const int row0 = (bid / gx) * 256;
  const int col0 = (bid % gx) * 256;
  const int NT = 16, NI = 8;

  // staging: thread t covers row (t>>3) (+64 for 2nd load), stored granule t&7.
  // 3-bit XOR key: stored_g = logical_g ^ ((row>>1)&7). Source pre-swizzled.
  const int scol = (((t & 7) ^ ((t >> 4) & 7)) << 3);   // elems
  const unsigned short* gA = A + (size_t)(row0 + (t >> 3)) * lda + scol;
  const unsigned short* gB = B + (size_t)(col0 + (t >> 3)) * ldb + scol;

  // stage half: op (0=A,1=B), h (0/1), dbuf d, K-tile tl (no guard here)
#define STG(op_, h_, d_, tl_) do { \
    const unsigned short* s0_ = (op_ ? gB : gA) + \
        (size_t)((h_) * 128) * (op_ ? ldb : lda) + (tl_) * 64; \
    const unsigned short* s1_ = s0_ + (size_t)64 * (op_ ? ldb : lda); \
    unsigned short* l0_ = &sh[(d_) * 32768 + (op_) * 16384 + (h_) * 8192 + t * 8]; \
    __builtin_amdgcn_global_load_lds((const GLB_AS void*)s0_, (LDS_AS void*)l0_, 16, 0, 0); \
    __builtin_amdgcn_global_load_lds((const GLB_AS void*)s1_, (LDS_AS void*)(l0_ + 4096), 16, 0, 0); \
  } while (0)

  // ds_read offsets: key = (fr>>1)&7 (independent of frag indices)
  const int fr = lane & 15;
  const int lh = lane >> 4;
  const int key = (fr >> 1) & 7;
  const int g0 = ((0 * 4 + lh) ^ key) << 3;   // kk=0 granule byte-elems
  const int g1 = ((1 * 4 + lh) ^ key) << 3;   // kk=1

  floatx4 acc[8][4] = {};
  bf16x8 afr[4][2], bfr0[2][2], bfr1[2][2];

#define RDA(d_, mh_) do { \
    _Pragma("unroll") for (int mf = 0; mf < 4; ++mf) { \
      const int rb_ = (d_) * 32768 + wm * 8192 + (((mh_) * 64 + mf * 16 + fr) << 6); \
      afr[mf][0] = *(const bf16x8*)&sh[rb_ + g0]; \
      afr[mf][1] = *(const bf16x8*)&sh[rb_ + g1]; } \
  } while (0)
#define RDB(d_, nh_, dst_) do { \
    _Pragma("unroll") for (int nf = 0; nf < 2; ++nf) { \
      const int rb_ = (d_) * 32768 + 16384 + (wn >> 1) * 8192 + \
                      ((((wn & 1) * 64 + (nh_) * 32 + nf * 16 + fr)) << 6); \
      dst_[nf][0] = *(const bf16x8*)&sh[rb_ + g0]; \
      dst_[nf][1] = *(const bf16x8*)&sh[rb_ + g1]; } \
  } while (0)
#define MFMA16(mh_, nh_, bsrc_) do { \
    __builtin_amdgcn_s_setprio(1); \
    _Pragma("unroll") for (int mf = 0; mf < 4; ++mf) \
      _Pragma("unroll") for (int nf = 0; nf < 2; ++nf) { \
        acc[(mh_)*4+mf][(nh_)*2+nf] = __builtin_amdgcn_mfma_f32_16x16x32_bf16(afr[mf][0], bsrc_[nf][0], acc[(mh_)*4+mf][(nh_)*2+nf], 0, 0, 0); \
        acc[(mh_)*4+mf][(nh_)*2+nf] = __builtin_amdgcn_mfma_f32_16x16x32_bf16(afr[mf][1], bsrc_[nf][1], acc[(mh_)*4+mf][(nh_)*2+nf], 0, 0, 0); } \
    __builtin_amdgcn_s_setprio(0); \
  } while (0)
#define BAR()  __builtin_amdgcn_s_barrier()
#define LGKM() do { asm volatile("s_waitcnt lgkmcnt(0)" ::: "memory"); \
                    __builtin_amdgcn_sched_barrier(0); } while (0)

  // prologue: tile0 {B0,A0,B1,A1} + tile1 {B0,A0}; all-tile0 landed -> vmcnt(4)
  STG(1, 0, 0, 0); STG(0, 0, 0, 0); STG(1, 1, 0, 0); STG(0, 1, 0, 0);
  STG(1, 0, 1, 1); STG(0, 0, 1, 1);
  asm volatile("s_waitcnt vmcnt(4)" ::: "memory");
  BAR();

  for (int j = 0; j < NI; ++j) {
    const bool more = (j < NI - 1);
    // ph1: reads A(d0,mh0)+B(d0,nh0); stage B1(tile 2j+1, d1)
    RDA(0, 0); RDB(0, 0, bfr0);
    STG(1, 1, 1, 2 * j + 1);
    BAR(); LGKM(); MFMA16(0, 0, bfr0); BAR();
    // ph2: reads B(d0,nh1); stage A1(2j+1, d1)
    RDB(0, 1, bfr1);
    STG(0, 1, 1, 2 * j + 1);
    BAR(); LGKM(); MFMA16(0, 1, bfr1); BAR();
    // ph3: reads A(d0,mh1); stage B0(2j+2, d0)
    RDA(0, 1);
    if (more) STG(1, 0, 0, 2 * j + 2);
    BAR(); LGKM(); MFMA16(1, 0, bfr0); BAR();
    // ph4: no reads; stage A0(2j+2, d0); wait: tile 2j+1 fully landed
    if (more) STG(0, 0, 0, 2 * j + 2);
    BAR(); LGKM(); MFMA16(1, 1, bfr1);
    if (j == NI - 1) { asm volatile("s_waitcnt vmcnt(0)" ::: "memory"); }
    else             { asm volatile("s_waitcnt vmcnt(4)" ::: "memory"); }
    BAR();
    // ph5: reads A(d1,mh0)+B(d1,nh0); stage B1(2j+2, d0)
    RDA(1, 0); RDB(1, 0, bfr0);
    if (more) STG(1, 1, 0, 2 * j + 2);
    BAR(); LGKM(); MFMA16(0, 0, bfr0); BAR();
    // ph6: reads B(d1,nh1); stage A1(2j+2, d0)
    RDB(1, 1, bfr1);
    if (more) STG(0, 1, 0, 2 * j + 2);
    BAR(); LGKM(); MFMA16(0, 1, bfr1); BAR();
    // ph7: reads A(d1,mh1); stage B0(2j+3, d1)
    RDA(1, 1);
    if (more) STG(1, 0, 1, 2 * j + 3);
    BAR(); LGKM(); MFMA16(1, 0, bfr0); BAR();
    // ph8: no reads; stage A0(2j+3, d1); wait: tile 2j+2 fully landed
    if (more) STG(0, 0, 1, 2 * j + 3);
    BAR(); LGKM(); MFMA16(1, 1, bfr1);
    asm volatile("s_waitcnt vmcnt(4)" ::: "memory");
    BAR();
  }
#undef STG
#undef RDA
#undef RDB
#undef MFMA16
#undef BAR
#undef LGKM

  // epilogue: exp + bf16 store + row-sum partials.
  // m = row0 + wm*128 + (ai>>2)*64 + (ai&3)*16 + er + r; n = col0 + wn*64 +
  // (bj>>1)*32 + (bj&1)*16 + ec.  [m89 C/D layout]
  const int er = (lane >> 4) * 4;
  const int ec = lane & 15;
  const int rj = ((col0 >> 6) + wn) * 4096;
#pragma unroll
  for (int ai = 0; ai < 8; ++ai) {
#pragma unroll
    for (int r = 0; r < 4; ++r) {
      const int m = row0 + wm * 128 + (ai >> 2) * 64 + (ai & 3) * 16 + er + r;
      float rsum = 0.f;
#pragma unroll
      for (int bj = 0; bj < 4; ++bj) {
        const float e = __expf(acc[ai][bj][r] * scale);
        Pb[(size_t)m * ldc + (col0 + wn * 64 + (bj >> 1) * 32 + (bj & 1) * 16 + ec)] = f2bf_u16(e);
        rsum += e;
      }
      rsum += __shfl_xor(rsum, 1);
      rsum += __shfl_xor(rsum, 2);
      rsum += __shfl_xor(rsum, 4);
      rsum += __shfl_xor(rsum, 8);
      if (ec == 0) rsp[rj + m] = rsum;
    }
  }
}

// ================= r9 GEMM (QKV / PV) =================
// EPI: 0 = PV (bf16 partial store to c[z]); 3 = QKV (qkb / transposed vT)
struct GemmOuts { void* c[4]; int ldc[4]; };

template <int EPI>
__global__ __launch_bounds__(256, 2) void gemm_bt(const unsigned short* __restrict__ A,
                                                  const unsigned short* __restrict__ B,
                                                  GemmOuts outs, int lda, int ldb,
                                                  int klen, float scale) {
  __shared__ unsigned short sh[24576];
  const int t = threadIdx.x;
  const int w = t >> 6, lane = t & 63;
  const int wm = w >> 1, wn = w & 1;
  const int gx = gridDim.x;
  const int nwg = gx * gridDim.y;
  int bid = blockIdx.y * gx + blockIdx.x;
  bid = (bid & 7) * (nwg >> 3) + (bid >> 3);
  const int row0 = (bid / gx) * 256;
  const int col0 = (bid % gx) * 128;
  const int z = blockIdx.z;
  const int kstart = z * klen;
  const int NT = klen >> 5;

  const int srow = t >> 2;
  const int scbe = (((t & 3) ^ ((t >> 3) & 3)) << 3);
  const unsigned short* gA0 = A + (size_t)(row0 + srow) * lda + kstart + scbe;
  const unsigned short* gA1 = gA0 + (size_t)64 * lda;
  const unsigned short* gA2 = gA0 + (size_t)128 * lda;
  const unsigned short* gA3 = gA0 + (size_t)192 * lda;
  const unsigned short* gB0 = B + (size_t)(col0 + srow) * ldb + kstart + scbe;
  const unsigned short* gB1 = gB0 + (size_t)64 * ldb;

#define STAGE(tl_) do { \
    const int bb_ = ((tl_) & 1) * 12288; \
    __builtin_amdgcn_global_load_lds((const GLB_AS void*)(gA0 + (tl_) * 32), \
        (LDS_AS void*)&sh[bb_ + t * 8], 16, 0, 0); \
    __builtin_amdgcn_global_load_lds((const GLB_AS void*)(gA1 + (tl_) * 32), \
        (LDS_AS void*)&sh[bb_ + 2048 + t * 8], 16, 0, 0); \
    __builtin_amdgcn_global_load_lds((const GLB_AS void*)(gA2 + (tl_) * 32), \
        (LDS_AS void*)&sh[bb_ + 4096 + t * 8], 16, 0, 0); \
    __builtin_amdgcn_global_load_lds((const GLB_AS void*)(gA3 + (tl_) * 32), \
        (LDS_AS void*)&sh[bb_ + 6144 + t * 8], 16, 0, 0); \
    __builtin_amdgcn_global_load_lds((const GLB_AS void*)(gB0 + (tl_) * 32), \
        (LDS_AS void*)&sh[bb_ + 8192 + t * 8], 16, 0, 0); \
    __builtin_amdgcn_global_load_lds((const GLB_AS void*)(gB1 + (tl_) * 32), \
        (LDS_AS void*)&sh[bb_ + 10240 + t * 8], 16, 0, 0); \
  } while (0)

  const int fr = lane & 15;
  const int sg = (((lane >> 4) ^ ((lane >> 1) & 3)) << 3);
  int aofs[8], bofs[4];
#pragma unroll
  for (int mf = 0; mf < 8; ++mf) aofs[mf] = ((wm * 128 + mf * 16 + fr) << 5) + sg;
#pragma unroll
  for (int nf = 0; nf < 4; ++nf) bofs[nf] = 8192 + ((wn * 64 + nf * 16 + fr) << 5) + sg;

  floatx4 acc[8][4] = {};

  STAGE(0);

  for (int tile = 0; tile < NT; ++tile) {
    if (tile + 1 < NT) {
      STAGE(tile + 1);
      asm volatile("s_waitcnt vmcnt(6)" ::: "memory");
    } else {
      asm volatile("s_waitcnt vmcnt(0)" ::: "memory");
    }
    __builtin_amdgcn_s_barrier();

    const int bo = (tile & 1) * 12288;
    bf16x8 af[8], bf[4];
#pragma unroll
    for (int mf = 0; mf < 8; ++mf) af[mf] = *(const bf16x8*)&sh[bo + aofs[mf]];
#pragma unroll
    for (int nf = 0; nf < 4; ++nf) bf[nf] = *(const bf16x8*)&sh[bo + bofs[nf]];
    __builtin_amdgcn_s_setprio(1);
#pragma unroll
    for (int mf = 0; mf < 8; ++mf)
#pragma unroll
      for (int nf = 0; nf < 4; ++nf)
        acc[mf][nf] = __builtin_amdgcn_mfma_f32_16x16x32_bf16(af[mf], bf[nf], acc[mf][nf], 0, 0, 0);
    __builtin_amdgcn_s_setprio(0);

    __builtin_amdgcn_s_barrier();
  }
#undef STAGE

  const int er = (lane >> 4) * 4;
  const int ec = lane & 15;

  if (EPI == 0) {
    unsigned short* Cb = (unsigned short*)outs.c[z];
    const int ldc = outs.ldc[z];
#pragma unroll
    for (int mf = 0; mf < 8; ++mf)
#pragma unroll
      for (int nf = 0; nf < 4; ++nf)
#pragma unroll
        for (int r = 0; r < 4; ++r)
          Cb[(size_t)(row0 + wm * 128 + mf * 16 + er + r) * ldc +
             (col0 + wn * 64 + nf * 16 + ec)] = f2bf_u16(acc[mf][nf][r] * scale);
  } else {
    if (col0 < 2048) {
      unsigned short* qkb = (unsigned short*)outs.c[0];
#pragma unroll
      for (int mf = 0; mf < 8; ++mf)
#pragma unroll
        for (int nf = 0; nf < 4; ++nf)
#pragma unroll
          for (int r = 0; r < 4; ++r)
            qkb[(size_t)(row0 + wm * 128 + mf * 16 + er + r) * 2048 +
                (col0 + wn * 64 + nf * 16 + ec)] = f2bf_u16(acc[mf][nf][r]);
    } else {
      unsigned short* vT = (unsigned short*)outs.c[1];
#pragma unroll
      for (int mf = 0; mf < 8; ++mf)
#pragma unroll
        for (int nf = 0; nf < 4; ++nf) {
          const int n = (col0 - 2048) + wn * 64 + nf * 16 + ec;
          const int mb = row0 + wm * 128 + mf * 16 + er;
          ushort4 o = make_ushort4(f2bf_u16(acc[mf][nf][0]), f2bf_u16(acc[mf][nf][1]),
                                   f2bf_u16(acc[mf][nf][2]), f2bf_u16(acc[mf][nf][3]));
          *reinterpret_cast<ushort4*>(&vT[(size_t)n * 4096 + mb]) = o;
        }
    }
  }
}

// ---------------- reduce: out[row] = (p0+p1)[row] / sum_j rsp[j][row] ----------------
__global__ __launch_bounds__(256) void reduce_pv(float* __restrict__ out,
                                                 const unsigned short* __restrict__ p0,
                                                 const unsigned short* __restrict__ p1,
                                                 const float* __restrict__ rsp) {
  const int row = blockIdx.x;
  const int lane = threadIdx.x & 63;
  float s = rsp[lane * 4096 + row];
#pragma unroll
  for (int off = 32; off >= 1; off >>= 1) s += __shfl_xor(s, off);
  const float inv = 1.0f / s;
  const int idx = row * 256 + threadIdx.x;
  ushort4 a = ((const ushort4*)p0)[idx];
  ushort4 b = ((const ushort4*)p1)[idx];
  float4 o;
  o.x = (bf2f(a.x) + bf2f(b.x)) * inv;
  o.y = (bf2f(a.y) + bf2f(b.y)) * inv;
  o.z = (bf2f(a.z) + bf2f(b.z)) * inv;
  o.w = (bf2f(a.w) + bf2f(b.w)) * inv;
  ((float4*)out)[idx] = o;
}

extern "C" void kernel_launch(void* const* d_in, const int* in_sizes, int n_in,
                              void* d_out, int out_size, void* d_ws, size_t ws_size,
                              hipStream_t stream) {
  const float* x  = (const float*)d_in[0];
  const float* Wq = (const float*)d_in[1];
  const float* Wk = (const float*)d_in[2];
  const float* Wv = (const float*)d_in[3];
  float* out = (float*)d_out;

  const int N = 4096, D = 1024;

  // workspace (~80 MB):
  // [0,32)   P bf16 [4096][4096] = exp(scores)
  // [32,48)  qkb bf16 [4096][2048]  (q | k)
  // [48,56)  vT bf16 [1024][4096]
  // [56,64)  xb bf16 [4096][1024]; reused as p0 after QKV
  // [64,70)  wb bf16 [3072][1024]
  // [70,71)  rsp f32 [64][4096]
  // [72,80)  p1 bf16 [4096][1024]
  char* ws = (char*)d_ws;
  unsigned short* P   = (unsigned short*)ws;
  unsigned short* qkb = (unsigned short*)(ws + (32u << 20));
  unsigned short* vT  = (unsigned short*)(ws + (48u << 20));
  unsigned short* xb  = (unsigned short*)(ws + (56u << 20));
  unsigned short* wb  = (unsigned short*)(ws + (64u << 20));
  float*          rsp = (float*)(ws + (70u << 20));
  unsigned short* p0  = xb;
  unsigned short* p1  = (unsigned short*)(ws + (72u << 20));

  // fused casts
  cast_all<<<7168, 256, 0, stream>>>(x, Wq, Wk, Wv, xb, wb);

  // qkv = x @ [Wq;Wk;Wv]^T : q,k -> qkb; v -> vT
  GemmOuts oq; oq.c[0] = qkb; oq.c[1] = vT; oq.c[2] = oq.c[3] = qkb;
  oq.ldc[0] = 2048; oq.ldc[1] = 4096; oq.ldc[2] = oq.ldc[3] = 2048;
  gemm_bt<3><<<dim3(3 * D / 128, N / 256, 1), 256, 0, stream>>>(xb, wb, oq, D, D, D, 1.0f);

  // P = exp((q @ k^T)/32); rsp = row-sum partials  — 8-phase 256x256 kernel
  gemm8p_s<<<dim3(N / 256, N / 256, 1), 512, 0, stream>>>(qkb, qkb + D, P, rsp,
                                                          2 * D, 2 * D, N, 0.03125f);

  // partials = P @ v, split-K x2 (bf16)
  GemmOuts op;
  op.c[0] = p0; op.ldc[0] = D;
  op.c[1] = p1; op.ldc[1] = D;
  op.c[2] = p0; op.ldc[2] = D;
  op.c[3] = p1; op.ldc[3] = D;
  gemm_bt<0><<<dim3(D / 128, N / 256, 2), 256, 0, stream>>>(P, vT, op, N, N, N / 2, 1.0f);

  // out = (p0+p1) / rowsum
  reduce_pv<<<N, 256, 0, stream>>>(out, p0, p1, rsp);
}

// Round 13
// 136.535 us; speedup vs baseline: 1.3130x; 1.0114x over previous
//
#include <hip/hip_runtime.h>

// SelfAttention: out = softmax((x Wq^T)(x Wk^T)^T / 32) (x Wv^T)
// N=4096, D=1024, f32 in/out; bf16 MFMA compute.
// v13 = r12 (best: 138.1us) with the two non-GEMM passes tuned to BW roofline:
//  - cast_all: per-block-uniform source (no per-thread branch), 32B/thread.
//  - reduce_pv: one wave per row (4x less rsp traffic, grid 1024).
// GEMM kernels verbatim from r12: S = 8-phase 256x256 (46.4us), QKV/PV =
// 256x128 2-phase prefetch-1 (46.4us PV) — seven schedule variants all pin
// ~740 TF at K=1024, so the GEMM rate is treated as fixed this session.

typedef __attribute__((ext_vector_type(8))) __bf16 bf16x8;
typedef __attribute__((ext_vector_type(4))) float floatx4;

#define GLB_AS __attribute__((address_space(1)))
#define LDS_AS __attribute__((address_space(3)))

static __device__ __forceinline__ unsigned short f2bf_u16(float f) {
  union { float f; unsigned u; } x; x.f = f;
  unsigned r = x.u;
  r += 0x7fffu + ((r >> 16) & 1u);   // RNE
  return (unsigned short)(r >> 16);
}
static __device__ __forceinline__ float bf2f(unsigned short u) {
  union { unsigned u; float f; } x; x.u = ((unsigned)u) << 16; return x.f;
}

// ---------------- cast f32 -> bf16, per-block-uniform source ----------------
// x: blocks [0,2048) ; Wq: [2048,2560) ; Wk: [2560,3072) ; Wv: [3072,3584).
// Each block covers 512 float4 (8 KB in / 4 KB out), 2 float4 per thread.
__global__ __launch_bounds__(256) void cast_all(const float* __restrict__ x,
                                                const float* __restrict__ Wq,
                                                const float* __restrict__ Wk,
                                                const float* __restrict__ Wv,
                                                unsigned short* __restrict__ xb,
                                                unsigned short* __restrict__ wb) {
  const int b = blockIdx.x;
  const float* src; unsigned short* dst; int k0;
  if (b < 2048)      { src = x;  dst = xb;                   k0 = b * 512; }
  else if (b < 2560) { src = Wq; dst = wb;                   k0 = (b - 2048) * 512; }
  else if (b < 3072) { src = Wk; dst = wb + 1024 * 1024;     k0 = (b - 2560) * 512; }
  else               { src = Wv; dst = wb + 2 * 1024 * 1024; k0 = (b - 3072) * 512; }
#pragma unroll
  for (int j = 0; j < 2; ++j) {
    const int k = k0 + j * 256 + threadIdx.x;
    float4 v = reinterpret_cast<const float4*>(src)[k];
    ushort4 o = make_ushort4(f2bf_u16(v.x), f2bf_u16(v.y), f2bf_u16(v.z), f2bf_u16(v.w));
    reinterpret_cast<ushort4*>(dst)[k] = o;
  }
}

// ================= 8-phase 256x256 S-GEMM (verbatim r12) =================
__global__ __launch_bounds__(512, 2) void gemm8p_s(const unsigned short* __restrict__ A,
                                                   const unsigned short* __restrict__ B,
                                                   unsigned short* __restrict__ Pb,
                                                   float* __restrict__ rsp,
                                                   int lda, int ldb, int ldc,
                                                   float scale) {
  __shared__ unsigned short sh[65536];
  const int t = threadIdx.x;
  const int w = t >> 6, lane = t & 63;
  const int wm = w >> 2, wn = w & 3;
  const int gx = gridDim.x;
  const int nwg = gx * gridDim.y;
  int bid = blockIdx.y * gx + blockIdx.x;
  bid = (bid & 7) * (nwg >> 3) + (bid >> 3);
  const int row0 = (bid / gx) * 256;
  const int col0 = (bid % gx) * 256;
  const int NI = 8;

  const int scol = (((t & 7) ^ ((t >> 4) & 7)) << 3);
  const unsigned short* gA = A + (size_t)(row0 + (t >> 3)) * lda + scol;
  const unsigned short* gB = B + (size_t)(col0 + (t >> 3)) * ldb + scol;

#define STG(op_, h_, d_, tl_) do { \
    const unsigned short* s0_ = (op_ ? gB : gA) + \
        (size_t)((h_) * 128) * (op_ ? ldb : lda) + (tl_) * 64; \
    const unsigned short* s1_ = s0_ + (size_t)64 * (op_ ? ldb : lda); \
    unsigned short* l0_ = &sh[(d_) * 32768 + (op_) * 16384 + (h_) * 8192 + t * 8]; \
    __builtin_amdgcn_global_load_lds((const GLB_AS void*)s0_, (LDS_AS void*)l0_, 16, 0, 0); \
    __builtin_amdgcn_global_load_lds((const GLB_AS void*)s1_, (LDS_AS void*)(l0_ + 4096), 16, 0, 0); \
  } while (0)

  const int fr = lane & 15;
  const int lh = lane >> 4;
  const int key = (fr >> 1) & 7;
  const int g0 = ((0 * 4 + lh) ^ key) << 3;
  const int g1 = ((1 * 4 + lh) ^ key) << 3;

  floatx4 acc[8][4] = {};
  bf16x8 afr[4][2], bfr0[2][2], bfr1[2][2];

#define RDA(d_, mh_) do { \
    _Pragma("unroll") for (int mf = 0; mf < 4; ++mf) { \
      const int rb_ = (d_) * 32768 + wm * 8192 + (((mh_) * 64 + mf * 16 + fr) << 6); \
      afr[mf][0] = *(const bf16x8*)&sh[rb_ + g0]; \
      afr[mf][1] = *(const bf16x8*)&sh[rb_ + g1]; } \
  } while (0)
#define RDB(d_, nh_, dst_) do { \
    _Pragma("unroll") for (int nf = 0; nf < 2; ++nf) { \
      const int rb_ = (d_) * 32768 + 16384 + (wn >> 1) * 8192 + \
                      ((((wn & 1) * 64 + (nh_) * 32 + nf * 16 + fr)) << 6); \
      dst_[nf][0] = *(const bf16x8*)&sh[rb_ + g0]; \
      dst_[nf][1] = *(const bf16x8*)&sh[rb_ + g1]; } \
  } while (0)
#define MFMA16(mh_, nh_, bsrc_) do { \
    __builtin_amdgcn_s_setprio(1); \
    _Pragma("unroll") for (int mf = 0; mf < 4; ++mf) \
      _Pragma("unroll") for (int nf = 0; nf < 2; ++nf) { \
        acc[(mh_)*4+mf][(nh_)*2+nf] = __builtin_amdgcn_mfma_f32_16x16x32_bf16(afr[mf][0], bsrc_[nf][0], acc[(mh_)*4+mf][(nh_)*2+nf], 0, 0, 0); \
        acc[(mh_)*4+mf][(nh_)*2+nf] = __builtin_amdgcn_mfma_f32_16x16x32_bf16(afr[mf][1], bsrc_[nf][1], acc[(mh_)*4+mf][(nh_)*2+nf], 0, 0, 0); } \
    __builtin_amdgcn_s_setprio(0); \
  } while (0)
#define BAR()  __builtin_amdgcn_s_barrier()
#define LGKM() do { asm volatile("s_waitcnt lgkmcnt(0)" ::: "memory"); \
                    __builtin_amdgcn_sched_barrier(0); } while (0)

  STG(1, 0, 0, 0); STG(0, 0, 0, 0); STG(1, 1, 0, 0); STG(0, 1, 0, 0);
  STG(1, 0, 1, 1); STG(0, 0, 1, 1);
  asm volatile("s_waitcnt vmcnt(4)" ::: "memory");
  BAR();

  for (int j = 0; j < NI; ++j) {
    const bool more = (j < NI - 1);
    RDA(0, 0); RDB(0, 0, bfr0);
    STG(1, 1, 1, 2 * j + 1);
    BAR(); LGKM(); MFMA16(0, 0, bfr0); BAR();
    RDB(0, 1, bfr1);
    STG(0, 1, 1, 2 * j + 1);
    BAR(); LGKM(); MFMA16(0, 1, bfr1); BAR();
    RDA(0, 1);
    if (more) STG(1, 0, 0, 2 * j + 2);
    BAR(); LGKM(); MFMA16(1, 0, bfr0); BAR();
    if (more) STG(0, 0, 0, 2 * j + 2);
    BAR(); LGKM(); MFMA16(1, 1, bfr1);
    if (j == NI - 1) { asm volatile("s_waitcnt vmcnt(0)" ::: "memory"); }
    else             { asm volatile("s_waitcnt vmcnt(4)" ::: "memory"); }
    BAR();
    RDA(1, 0); RDB(1, 0, bfr0);
    if (more) STG(1, 1, 0, 2 * j + 2);
    BAR(); LGKM(); MFMA16(0, 0, bfr0); BAR();
    RDB(1, 1, bfr1);
    if (more) STG(0, 1, 0, 2 * j + 2);
    BAR(); LGKM(); MFMA16(0, 1, bfr1); BAR();
    RDA(1, 1);
    if (more) STG(1, 0, 1, 2 * j + 3);
    BAR(); LGKM(); MFMA16(1, 0, bfr0); BAR();
    if (more) STG(0, 0, 1, 2 * j + 3);
    BAR(); LGKM(); MFMA16(1, 1, bfr1);
    asm volatile("s_waitcnt vmcnt(4)" ::: "memory");
    BAR();
  }
#undef STG
#undef RDA
#undef RDB
#undef MFMA16
#undef BAR
#undef LGKM

  const int er = (lane >> 4) * 4;
  const int ec = lane & 15;
  const int rj = ((col0 >> 6) + wn) * 4096;
#pragma unroll
  for (int ai = 0; ai < 8; ++ai) {
#pragma unroll
    for (int r = 0; r < 4; ++r) {
      const int m = row0 + wm * 128 + (ai >> 2) * 64 + (ai & 3) * 16 + er + r;
      float rsum = 0.f;
#pragma unroll
      for (int bj = 0; bj < 4; ++bj) {
        const float e = __expf(acc[ai][bj][r] * scale);
        Pb[(size_t)m * ldc + (col0 + wn * 64 + (bj >> 1) * 32 + (bj & 1) * 16 + ec)] = f2bf_u16(e);
        rsum += e;
      }
      rsum += __shfl_xor(rsum, 1);
      rsum += __shfl_xor(rsum, 2);
      rsum += __shfl_xor(rsum, 4);
      rsum += __shfl_xor(rsum, 8);
      if (ec == 0) rsp[rj + m] = rsum;
    }
  }
}

// ================= r9 GEMM (QKV / PV, verbatim) =================
struct GemmOuts { void* c[4]; int ldc[4]; };

template <int EPI>
__global__ __launch_bounds__(256, 2) void gemm_bt(const unsigned short* __restrict__ A,
                                                  const unsigned short* __restrict__ B,
                                                  GemmOuts outs, int lda, int ldb,
                                                  int klen, float scale) {
  __shared__ unsigned short sh[24576];
  const int t = threadIdx.x;
  const int w = t >> 6, lane = t & 63;
  const int wm = w >> 1, wn = w & 1;
  const int gx = gridDim.x;
  const int nwg = gx * gridDim.y;
  int bid = blockIdx.y * gx + blockIdx.x;
  bid = (bid & 7) * (nwg >> 3) + (bid >> 3);
  const int row0 = (bid / gx) * 256;
  const int col0 = (bid % gx) * 128;
  const int z = blockIdx.z;
  const int kstart = z * klen;
  const int NT = klen >> 5;

  const int srow = t >> 2;
  const int scbe = (((t & 3) ^ ((t >> 3) & 3)) << 3);
  const unsigned short* gA0 = A + (size_t)(row0 + srow) * lda + kstart + scbe;
  const unsigned short* gA1 = gA0 + (size_t)64 * lda;
  const unsigned short* gA2 = gA0 + (size_t)128 * lda;
  const unsigned short* gA3 = gA0 + (size_t)192 * lda;
  const unsigned short* gB0 = B + (size_t)(col0 + srow) * ldb + kstart + scbe;
  const unsigned short* gB1 = gB0 + (size_t)64 * ldb;

#define STAGE(tl_) do { \
    const int bb_ = ((tl_) & 1) * 12288; \
    __builtin_amdgcn_global_load_lds((const GLB_AS void*)(gA0 + (tl_) * 32), \
        (LDS_AS void*)&sh[bb_ + t * 8], 16, 0, 0); \
    __builtin_amdgcn_global_load_lds((const GLB_AS void*)(gA1 + (tl_) * 32), \
        (LDS_AS void*)&sh[bb_ + 2048 + t * 8], 16, 0, 0); \
    __builtin_amdgcn_global_load_lds((const GLB_AS void*)(gA2 + (tl_) * 32), \
        (LDS_AS void*)&sh[bb_ + 4096 + t * 8], 16, 0, 0); \
    __builtin_amdgcn_global_load_lds((const GLB_AS void*)(gA3 + (tl_) * 32), \
        (LDS_AS void*)&sh[bb_ + 6144 + t * 8], 16, 0, 0); \
    __builtin_amdgcn_global_load_lds((const GLB_AS void*)(gB0 + (tl_) * 32), \
        (LDS_AS void*)&sh[bb_ + 8192 + t * 8], 16, 0, 0); \
    __builtin_amdgcn_global_load_lds((const GLB_AS void*)(gB1 + (tl_) * 32), \
        (LDS_AS void*)&sh[bb_ + 10240 + t * 8], 16, 0, 0); \
  } while (0)

  const int fr = lane & 15;
  const int sg = (((lane >> 4) ^ ((lane >> 1) & 3)) << 3);
  int aofs[8], bofs[4];
#pragma unroll
  for (int mf = 0; mf < 8; ++mf) aofs[mf] = ((wm * 128 + mf * 16 + fr) << 5) + sg;
#pragma unroll
  for (int nf = 0; nf < 4; ++nf) bofs[nf] = 8192 + ((wn * 64 + nf * 16 + fr) << 5) + sg;

  floatx4 acc[8][4] = {};

  STAGE(0);

  for (int tile = 0; tile < NT; ++tile) {
    if (tile + 1 < NT) {
      STAGE(tile + 1);
      asm volatile("s_waitcnt vmcnt(6)" ::: "memory");
    } else {
      asm volatile("s_waitcnt vmcnt(0)" ::: "memory");
    }
    __builtin_amdgcn_s_barrier();

    const int bo = (tile & 1) * 12288;
    bf16x8 af[8], bf[4];
#pragma unroll
    for (int mf = 0; mf < 8; ++mf) af[mf] = *(const bf16x8*)&sh[bo + aofs[mf]];
#pragma unroll
    for (int nf = 0; nf < 4; ++nf) bf[nf] = *(const bf16x8*)&sh[bo + bofs[nf]];
    __builtin_amdgcn_s_setprio(1);
#pragma unroll
    for (int mf = 0; mf < 8; ++mf)
#pragma unroll
      for (int nf = 0; nf < 4; ++nf)
        acc[mf][nf] = __builtin_amdgcn_mfma_f32_16x16x32_bf16(af[mf], bf[nf], acc[mf][nf], 0, 0, 0);
    __builtin_amdgcn_s_setprio(0);

    __builtin_amdgcn_s_barrier();
  }
#undef STAGE

  const int er = (lane >> 4) * 4;
  const int ec = lane & 15;

  if (EPI == 0) {
    unsigned short* Cb = (unsigned short*)outs.c[z];
    const int ldc = outs.ldc[z];
#pragma unroll
    for (int mf = 0; mf < 8; ++mf)
#pragma unroll
      for (int nf = 0; nf < 4; ++nf)
#pragma unroll
        for (int r = 0; r < 4; ++r)
          Cb[(size_t)(row0 + wm * 128 + mf * 16 + er + r) * ldc +
             (col0 + wn * 64 + nf * 16 + ec)] = f2bf_u16(acc[mf][nf][r] * scale);
  } else {
    if (col0 < 2048) {
      unsigned short* qkb = (unsigned short*)outs.c[0];
#pragma unroll
      for (int mf = 0; mf < 8; ++mf)
#pragma unroll
        for (int nf = 0; nf < 4; ++nf)
#pragma unroll
          for (int r = 0; r < 4; ++r)
            qkb[(size_t)(row0 + wm * 128 + mf * 16 + er + r) * 2048 +
                (col0 + wn * 64 + nf * 16 + ec)] = f2bf_u16(acc[mf][nf][r]);
    } else {
      unsigned short* vT = (unsigned short*)outs.c[1];
#pragma unroll
      for (int mf = 0; mf < 8; ++mf)
#pragma unroll
        for (int nf = 0; nf < 4; ++nf) {
          const int n = (col0 - 2048) + wn * 64 + nf * 16 + ec;
          const int mb = row0 + wm * 128 + mf * 16 + er;
          ushort4 o = make_ushort4(f2bf_u16(acc[mf][nf][0]), f2bf_u16(acc[mf][nf][1]),
                                   f2bf_u16(acc[mf][nf][2]), f2bf_u16(acc[mf][nf][3]));
          *reinterpret_cast<ushort4*>(&vT[(size_t)n * 4096 + mb]) = o;
        }
    }
  }
}

// ---------------- reduce: one wave per row ----------------
__global__ __launch_bounds__(256) void reduce_pv(float* __restrict__ out,
                                                 const unsigned short* __restrict__ p0,
                                                 const unsigned short* __restrict__ p1,
                                                 const float* __restrict__ rsp) {
  const int w = threadIdx.x >> 6, lane = threadIdx.x & 63;
  const int row = blockIdx.x * 4 + w;
  float s = rsp[lane * 4096 + row];
#pragma unroll
  for (int off = 32; off >= 1; off >>= 1) s += __shfl_xor(s, off);
  const float inv = 1.0f / s;
#pragma unroll
  for (int j = 0; j < 4; ++j) {
    const int idx = row * 256 + j * 64 + lane;   // ushort4 / float4 index
    ushort4 a = ((const ushort4*)p0)[idx];
    ushort4 b = ((const ushort4*)p1)[idx];
    float4 o;
    o.x = (bf2f(a.x) + bf2f(b.x)) * inv;
    o.y = (bf2f(a.y) + bf2f(b.y)) * inv;
    o.z = (bf2f(a.z) + bf2f(b.z)) * inv;
    o.w = (bf2f(a.w) + bf2f(b.w)) * inv;
    ((float4*)out)[idx] = o;
  }
}

extern "C" void kernel_launch(void* const* d_in, const int* in_sizes, int n_in,
                              void* d_out, int out_size, void* d_ws, size_t ws_size,
                              hipStream_t stream) {
  const float* x  = (const float*)d_in[0];
  const float* Wq = (const float*)d_in[1];
  const float* Wk = (const float*)d_in[2];
  const float* Wv = (const float*)d_in[3];
  float* out = (float*)d_out;

  const int N = 4096, D = 1024;

  // workspace (~80 MB):
  // [0,32)   P bf16 [4096][4096] = exp(scores)
  // [32,48)  qkb bf16 [4096][2048]  (q | k)
  // [48,56)  vT bf16 [1024][4096]
  // [56,64)  xb bf16 [4096][1024]; reused as p0 after QKV
  // [64,70)  wb bf16 [3072][1024]
  // [70,71)  rsp f32 [64][4096]
  // [72,80)  p1 bf16 [4096][1024]
  char* ws = (char*)d_ws;
  unsigned short* P   = (unsigned short*)ws;
  unsigned short* qkb = (unsigned short*)(ws + (32u << 20));
  unsigned short* vT  = (unsigned short*)(ws + (48u << 20));
  unsigned short* xb  = (unsigned short*)(ws + (56u << 20));
  unsigned short* wb  = (unsigned short*)(ws + (64u << 20));
  float*          rsp = (float*)(ws + (70u << 20));
  unsigned short* p0  = xb;
  unsigned short* p1  = (unsigned short*)(ws + (72u << 20));

  // casts (per-block-uniform source)
  cast_all<<<3584, 256, 0, stream>>>(x, Wq, Wk, Wv, xb, wb);

  // qkv = x @ [Wq;Wk;Wv]^T : q,k -> qkb; v -> vT
  GemmOuts oq; oq.c[0] = qkb; oq.c[1] = vT; oq.c[2] = oq.c[3] = qkb;
  oq.ldc[0] = 2048; oq.ldc[1] = 4096; oq.ldc[2] = oq.ldc[3] = 2048;
  gemm_bt<3><<<dim3(3 * D / 128, N / 256, 1), 256, 0, stream>>>(xb, wb, oq, D, D, D, 1.0f);

  // P = exp((q @ k^T)/32); rsp = row-sum partials  — 8-phase 256x256 kernel
  gemm8p_s<<<dim3(N / 256, N / 256, 1), 512, 0, stream>>>(qkb, qkb + D, P, rsp,
                                                          2 * D, 2 * D, N, 0.03125f);

  // partials = P @ v, split-K x2 (bf16)
  GemmOuts op;
  op.c[0] = p0; op.ldc[0] = D;
  op.c[1] = p1; op.ldc[1] = D;
  op.c[2] = p0; op.ldc[2] = D;
  op.c[3] = p1; op.ldc[3] = D;
  gemm_bt<0><<<dim3(D / 128, N / 256, 2), 256, 0, stream>>>(P, vT, op, N, N, N / 2, 1.0f);

  // out = (p0+p1) / rowsum  (one wave per row)
  reduce_pv<<<1024, 256, 0, stream>>>(out, p0, p1, rsp);
}